// Round 2
// baseline (29.043 us; speedup 1.0000x reference)
//
#include <hip/hip_runtime.h>
#include <math.h>

// Problem constants (from reference)
constexpr int B       = 256;
constexpr int C       = 8;
constexpr int LEN_TS  = 4096;
constexpr int K       = 128;
constexpr int DIM     = 3;
constexpr int START   = 0;          // max(0, 1000-1024)
constexpr int END     = 2152;       // min(4096, 1128+1024)
constexpr int PIS_LEN = END - START;        // 2152
constexpr int OUTW    = PIS_LEN - K + 1;    // 2025
constexpr float INV_NORM      = 0.1f;       // 1/NORM
constexpr float ALPHA         = -10.0f;
constexpr float BNORM         = 100.0f;
constexpr float MAX_CI        = 3.0f;
constexpr float MAX_NORM_DIST = 1e-5f;

constexpr int W      = 4;                   // consecutive windows per thread
constexpr int TPB    = 512;
constexpr int NWAVES = TPB / 64;
constexpr int NSTEP  = (K + W - 1 + 3) / 4; // 33 float4 steps covering 132 positions
// max position read: o0_max + 4*NSTEP - 1 = 4*511 + 131 = 2175 -> pad to 2176
constexpr int PIS_PAD = 4 * (TPB - 1) + 4 * NSTEP;  // 2176

__global__ __launch_bounds__(TPB)
void pis_dist_block_kernel(const float* __restrict__ x,
                           const float* __restrict__ shapelet,
                           float* __restrict__ out) {
    __shared__ __align__(16) float s_pis[PIS_PAD];
    __shared__ __align__(16) float s_sh[K + 4];
    __shared__ float s_red[2][NWAVES];

    const int b   = blockIdx.x;
    const int tid = threadIdx.x;

    // ---- stage pis slice into LDS (float4, coalesced; base is 16KB-aligned) ----
    const float* xrow = x + ((size_t)b * C + DIM) * LEN_TS + START;
    const float4* xr4 = reinterpret_cast<const float4*>(xrow);
    float4* sp4 = reinterpret_cast<float4*>(s_pis);
    for (int i = tid; i < PIS_LEN / 4; i += TPB) sp4[i] = xr4[i];
    if (tid < (PIS_PAD - PIS_LEN)) s_pis[PIS_LEN + tid] = 0.0f;  // zero pad
    if (tid < K) s_sh[tid] = shapelet[tid];
    if (tid < 4) s_sh[K + tid] = 0.0f;
    __syncthreads();

    // ---- ci_sh: 64-lane butterfly reduce (each lane covers 2 elements) ----
    const int lane = tid & 63;
    float ci_sh;
    {
        float d0 = s_sh[lane + 1] - s_sh[lane];
        float c  = d0 * d0;
        float d1 = s_sh[lane + 65] - s_sh[lane + 64];
        if (lane + 64 < K - 1) c = fmaf(d1, d1, c);
        #pragma unroll
        for (int off = 32; off; off >>= 1) c += __shfl_xor(c, off);
        ci_sh = c + INV_NORM;
    }

    // ---- main: W=4 consecutive windows per thread, float4 LDS reads ----
    const int o0 = tid * W;                 // multiple of 4 -> aligned
    float sumsq[W]   = {0.f, 0.f, 0.f, 0.f};
    float startcs[W];
    float endcs[W];
    startcs[0] = 0.f;
    // avoid "maybe-uninitialized" paths (all are statically assigned below)
    startcs[1] = startcs[2] = startcs[3] = 0.f;
    endcs[0] = endcs[1] = endcs[2] = endcs[3] = 0.f;
    float cs   = 0.f;
    float prev = 0.f;                       // unused at step 0 (j=-1 skipped)
    float shp[4] = {0.f, 0.f, 0.f, 0.f};    // sh[4i-4 .. 4i-1]

    const float4* pis4 = reinterpret_cast<const float4*>(s_pis);
    const float4* sh4  = reinterpret_cast<const float4*>(s_sh);

    #pragma unroll
    for (int i = 0; i < NSTEP; ++i) {
        float4 p = pis4[tid + i];           // positions o0+4i .. o0+4i+3
        float pp[4] = {p.x, p.y, p.z, p.w};
        float shc[4];
        if (i < K / 4) {                    // sh[4i .. 4i+3]
            float4 s4 = sh4[i];
            shc[0] = s4.x; shc[1] = s4.y; shc[2] = s4.z; shc[3] = s4.w;
        } else {
            shc[0] = shc[1] = shc[2] = shc[3] = 0.f;
        }
        #pragma unroll
        for (int r = 0; r < 4; ++r) {
            const int q = 4 * i + r;        // relative position
            const int j = q - 1;            // d2 index: (p[j], p[j+1])
            if (j >= 0 && j <= K + W - 3) { // j <= 129
                float pj = (r == 0) ? prev : pp[r - 1];
                float dd = pp[r] - pj;
                cs = fmaf(dd, dd, cs);
                if (j == 0) startcs[1] = cs;
                if (j == 1) startcs[2] = cs;
                if (j == 2) startcs[3] = cs;
                if (j == K - 2)     endcs[0] = cs;   // 126
                if (j == K - 1)     endcs[1] = cs;   // 127
                if (j == K)         endcs[2] = cs;   // 128
                if (j == K + 1)     endcs[3] = cs;   // 129
            }
            #pragma unroll
            for (int w = 0; w < W; ++w) {
                const int s = q - w;        // shapelet index for window w
                if (s >= 0 && s < K) {
                    float sv = (r >= w) ? shc[r - w] : shp[4 + r - w];
                    float df = pp[r] - sv;
                    sumsq[w] = fmaf(df, df, sumsq[w]);
                }
            }
        }
        prev = pp[3];
        shp[0] = shc[0]; shp[1] = shc[1]; shp[2] = shc[2]; shp[3] = shc[3];
    }

    // ---- epilogue: per-window softmin contributions ----
    float wd_sum = 0.f, w_sum = 0.f;
    #pragma unroll
    for (int w = 0; w < W; ++w) {
        if (o0 + w < OUTW) {
            float ci_pis  = (endcs[w] - startcs[w]) + INV_NORM;
            float mx      = fmaxf(ci_pis, ci_sh);
            float mn      = fminf(ci_pis, ci_sh);
            float ci_dist = fminf(mx / mn, MAX_CI);
            float dist    = sumsq[w] * ci_dist * (1.0f / (float)K);
            float d       = dist * (1.0f / BNORM);
            float wt      = __expf(ALPHA * d);
            wd_sum = fmaf(wt, d, wd_sum);
            w_sum += wt;
        }
    }

    // ---- block reduction ----
    #pragma unroll
    for (int off = 32; off; off >>= 1) {
        wd_sum += __shfl_down(wd_sum, off);
        w_sum  += __shfl_down(w_sum, off);
    }
    const int wv = tid >> 6;
    if (lane == 0) {
        s_red[0][wv] = wd_sum;
        s_red[1][wv] = w_sum;
    }
    __syncthreads();
    if (tid == 0) {
        float wd = 0.f, wt = 0.f;
        #pragma unroll
        for (int i = 0; i < NWAVES; ++i) {
            wd += s_red[0][i];
            wt += s_red[1][i];
        }
        float softmin = wd / wt * BNORM;
        out[b] = 1.0f - softmin / MAX_NORM_DIST;
    }
}

extern "C" void kernel_launch(void* const* d_in, const int* in_sizes, int n_in,
                              void* d_out, int out_size, void* d_ws, size_t ws_size,
                              hipStream_t stream) {
    const float* x        = (const float*)d_in[0];
    const float* shapelet = (const float*)d_in[1];
    float* out            = (float*)d_out;
    pis_dist_block_kernel<<<B, TPB, 0, stream>>>(x, shapelet, out);
}